// Round 3
// baseline (336.064 us; speedup 1.0000x reference)
//
#include <hip/hip_runtime.h>

#define NB 8192
#define NT 365
#define NF 5
#define NH 10
#define NG 40   // 4*NH

// Quad-lane broadcast via DPP quad_perm: all 4 lanes of a quad receive the
// value from quad-lane SRC. ctrl = SRC * 0b01010101.
template<int CTRL>
__device__ __forceinline__ float qb(float v) {
    return __int_as_float(
        __builtin_amdgcn_mov_dpp(__float_as_int(v), CTRL, 0xF, 0xF, true));
}

// 4 lanes per batch element; lane q (tid&3) owns gate block q in the order
// f, i, o, g (reference: jnp.split(gates, 4, axis=1)).
// Each lane holds its 10 columns of W_ih (50), W_hh (100), bias (10) in
// registers. h,c are replicated across the quad via DPP broadcasts of the
// activated gates, so the recurrent state never touches LDS/global.
__global__ __launch_bounds__(64)
void lstm_fused(const float* __restrict__ x,
                const float* __restrict__ w_ih,
                const float* __restrict__ w_hh,
                const float* __restrict__ bias,
                const float* __restrict__ fc_w,
                const float* __restrict__ fc_b,
                float* __restrict__ out)
{
    const int tid = blockIdx.x * 64 + threadIdx.x;
    const int lq  = tid & 3;    // quad lane = gate block
    const int b   = tid >> 2;   // batch element

    float* h_out = out + NB;
    float* c_out = out + NB + (size_t)NB * NT * NH;

    // ---- load this lane's weight columns [10*lq, 10*lq+10) ----
    const int c0 = lq * NH;
    float wih[NF][NH], whh[NH][NH], bs[NH];
    #pragma unroll
    for (int f = 0; f < NF; ++f)
        #pragma unroll
        for (int k = 0; k < NH; ++k) wih[f][k] = w_ih[f * NG + c0 + k];
    #pragma unroll
    for (int j = 0; j < NH; ++j)
        #pragma unroll
        for (int k = 0; k < NH; ++k) whh[j][k] = w_hh[j * NG + c0 + k];
    #pragma unroll
    for (int k = 0; k < NH; ++k) bs[k] = bias[c0 + k];

    float h[NH], c[NH];
    #pragma unroll
    for (int k = 0; k < NH; ++k) { h[k] = 0.f; c[k] = 0.f; }

    // gate block 3 (g) needs tanh = 2*sigmoid(2x)-1; others sigmoid(x).
    // sigmoid(s*x) = 1/(1+exp(-s*x)) -> store negated scale for the exp arg.
    const float sc  = (lq == 3) ? -2.0f : -1.0f;
    const bool  isg = (lq == 3);

    const float* xp = x + (size_t)b * NT * NF;
    float* hp = h_out + (size_t)b * NT * NH;
    float* cp = c_out + (size_t)b * NT * NH;
    // store split: lane0 -> h[0..4], lane1 -> h[5..9], lane2 -> c[0..4], lane3 -> c[5..9]
    float* sbase = ((lq < 2) ? hp : cp) + (lq & 1) * 5;

    float xv[NF];
    #pragma unroll
    for (int f = 0; f < NF; ++f) xv[f] = xp[f];

    for (int t = 0; t < NT; ++t) {
        // prefetch next timestep's x (clamped) so the load hides under compute
        float xn[NF];
        const float* xnp = xp + (size_t)((t + 1 < NT) ? (t + 1) : t) * NF;
        #pragma unroll
        for (int f = 0; f < NF; ++f) xn[f] = xnp[f];

        // ---- this lane's 10 gate pre-activations + activation ----
        float y[NH];
        #pragma unroll
        for (int k = 0; k < NH; ++k) {
            float r = bs[k];
            #pragma unroll
            for (int f = 0; f < NF; ++f) r = fmaf(xv[f], wih[f][k], r);
            #pragma unroll
            for (int j = 0; j < NH; ++j) r = fmaf(h[j], whh[j][k], r);
            float e = __expf(sc * r);
            float s = __builtin_amdgcn_rcpf(1.0f + e);
            y[k] = isg ? fmaf(2.0f, s, -1.0f) : s;  // uniform-per-lane select
        }

        // ---- broadcast activated gates across the quad; replicated h,c update ----
        #pragma unroll
        for (int k = 0; k < NH; ++k) {
            float yf = qb<0x00>(y[k]);   // sigmoid(f) from lane 0
            float yi = qb<0x55>(y[k]);   // sigmoid(i) from lane 1
            float yo = qb<0xAA>(y[k]);   // sigmoid(o) from lane 2
            float tg = qb<0xFF>(y[k]);   // tanh(g)    from lane 3
            float cn = fmaf(yf, c[k], yi * tg);
            c[k] = cn;
            float e2 = __expf(-2.0f * cn);
            float th = fmaf(2.0f, __builtin_amdgcn_rcpf(1.0f + e2), -1.0f);
            h[k] = yo * th;
        }

        // ---- store this lane's quarter of (h,c) ----
        float* dst = sbase + (size_t)t * NH;
        #pragma unroll
        for (int k = 0; k < 5; ++k) {
            float hv = (lq & 1) ? h[k + 5] : h[k];   // constant reg indices only
            float cv = (lq & 1) ? c[k + 5] : c[k];
            dst[k] = (lq < 2) ? hv : cv;
        }

        #pragma unroll
        for (int f = 0; f < NF; ++f) xv[f] = xn[f];
    }

    // ---- fc head on the final h (h is replicated; lane 0 stores) ----
    if (lq == 0) {
        float acc = fc_b[0];
        #pragma unroll
        for (int k = 0; k < NH; ++k) acc = fmaf(h[k], fc_w[k], acc);
        out[b] = acc;
    }
}

extern "C" void kernel_launch(void* const* d_in, const int* in_sizes, int n_in,
                              void* d_out, int out_size, void* d_ws, size_t ws_size,
                              hipStream_t stream) {
    const float* x    = (const float*)d_in[0];
    const float* wih  = (const float*)d_in[1];
    const float* whh  = (const float*)d_in[2];
    const float* bias = (const float*)d_in[3];
    const float* fcw  = (const float*)d_in[4];
    const float* fcb  = (const float*)d_in[5];
    float* out = (float*)d_out;

    const int threads = NB * 4;          // 4 lanes per batch element
    const int block = 64;
    lstm_fused<<<threads / block, block, 0, stream>>>(x, wih, whh, bias, fcw, fcb, out);
}

// Round 7
// 253.742 us; speedup vs baseline: 1.3244x; 1.3244x over previous
//
#include <hip/hip_runtime.h>

#define NB 8192
#define NT 365
#define NF 5
#define NH 10
#define NHH 5   // NH/2
#define NG 40   // 4*NH

// Quad broadcast via DPP quad_perm (works within each aligned 4-lane quad).
template<int CTRL>
__device__ __forceinline__ float qb(float v) {
    return __int_as_float(
        __builtin_amdgcn_mov_dpp(__float_as_int(v), CTRL, 0xF, 0xF, true));
}

// Exchange with lane^4 (pairs the two quads of an 8-lane group).
// BitMode: offset = (xor<<10)|(or<<5)|and = (4<<10)|0x1F = 0x101F.
__device__ __forceinline__ float xswap4(float v) {
    return __int_as_float(
        __builtin_amdgcn_ds_swizzle(__float_as_int(v), 0x101F));
}

// 8 lanes per batch element: lane = (half<<2)|lq.
//   lq   = lane&3  -> gate block f,i,o,g  (jnp.split order)
//   half = lane>>2 -> hidden columns [half*5, half*5+5)
// Each lane holds 5 weight columns in VGPRs (W_ih 25, W_hh 50, bias 5).
// Gates broadcast within each quad via DPP; c is kept per-half (replicated
// within the quad); the two h-halves are exchanged with ds_swizzle xor-4 so
// every lane enters the next step with the full h[0..9].
__global__ __launch_bounds__(256)
void lstm_fused8(const float* __restrict__ x,
                 const float* __restrict__ w_ih,
                 const float* __restrict__ w_hh,
                 const float* __restrict__ bias,
                 const float* __restrict__ fc_w,
                 const float* __restrict__ fc_b,
                 float* __restrict__ out)
{
    const int tid  = blockIdx.x * 256 + threadIdx.x;
    const int lq   = tid & 3;          // gate
    const int half = (tid >> 2) & 1;   // hidden half
    const int b    = tid >> 3;         // batch element

    float* h_out = out + NB;
    float* c_out = h_out + (size_t)NB * NT * NH;

    const int col0 = lq * NH + half * NHH;

    float wih[NF][NHH], whh[NH][NHH], bs[NHH];
    #pragma unroll
    for (int f = 0; f < NF; ++f)
        #pragma unroll
        for (int k = 0; k < NHH; ++k) wih[f][k] = w_ih[f * NG + col0 + k];
    #pragma unroll
    for (int j = 0; j < NH; ++j)
        #pragma unroll
        for (int k = 0; k < NHH; ++k) whh[j][k] = w_hh[j * NG + col0 + k];
    #pragma unroll
    for (int k = 0; k < NHH; ++k) bs[k] = bias[col0 + k];

    float h[NH], c[NHH];
    #pragma unroll
    for (int j = 0; j < NH; ++j) h[j] = 0.f;
    #pragma unroll
    for (int k = 0; k < NHH; ++k) c[k] = 0.f;

    // gate g needs tanh = 2*sigmoid(2x)-1; others sigmoid(x).
    const float sc  = (lq == 3) ? -2.0f : -1.0f;
    const bool  isg = (lq == 3);

    const float* xp = x + (size_t)b * NT * NF;
    float* hb = h_out + (size_t)b * NT * NH + half * NHH;
    float* cb = c_out + (size_t)b * NT * NH + half * NHH;
    // store split within quad: even lq -> A[0..2] at +0..2, odd lq -> A[3..4]
    // at +3..4, where A = h-half (lq<2) or c-half (lq>=2).
    float* sb = ((lq < 2) ? hb : cb) + ((lq & 1) ? 3 : 0);

    float xv[NF];
    #pragma unroll
    for (int f = 0; f < NF; ++f) xv[f] = xp[f];

    for (int t = 0; t < NT; ++t) {
        // prefetch next timestep's x (clamped)
        float xn[NF];
        const float* xnp = xp + (size_t)((t + 1 < NT) ? (t + 1) : t) * NF;
        #pragma unroll
        for (int f = 0; f < NF; ++f) xn[f] = xnp[f];

        // ---- 5 gate pre-activations + activation ----
        float y[NHH];
        #pragma unroll
        for (int k = 0; k < NHH; ++k) {
            float r = bs[k];
            #pragma unroll
            for (int f = 0; f < NF; ++f) r = fmaf(xv[f], wih[f][k], r);
            #pragma unroll
            for (int j = 0; j < NH; ++j) r = fmaf(h[j], whh[j][k], r);
            float e = __expf(sc * r);
            float s = __builtin_amdgcn_rcpf(1.0f + e);
            y[k] = isg ? fmaf(2.0f, s, -1.0f) : s;
        }

        // ---- quad broadcast + per-half c,h update (replicated in quad) ----
        float hh[NHH];
        #pragma unroll
        for (int k = 0; k < NHH; ++k) {
            float yf = qb<0x00>(y[k]);   // sigmoid(f)
            float yi = qb<0x55>(y[k]);   // sigmoid(i)
            float yo = qb<0xAA>(y[k]);   // sigmoid(o)
            float tg = qb<0xFF>(y[k]);   // tanh(g)
            float cn = fmaf(yf, c[k], yi * tg);
            c[k] = cn;
            float e2 = __expf(-2.0f * cn);
            float th = fmaf(2.0f, __builtin_amdgcn_rcpf(1.0f + e2), -1.0f);
            hh[k] = yo * th;
        }

        // ---- exchange h-halves across the two quads ----
        float ho[NHH];
        #pragma unroll
        for (int k = 0; k < NHH; ++k) ho[k] = xswap4(hh[k]);
        #pragma unroll
        for (int k = 0; k < NHH; ++k) {
            h[k]       = half ? ho[k] : hh[k];
            h[k + NHH] = half ? hh[k] : ho[k];
        }

        // ---- store this lane's 2-3 elements of (h,c) ----
        float a0 = (lq < 2) ? hh[0] : c[0];
        float a1 = (lq < 2) ? hh[1] : c[1];
        float a2 = (lq < 2) ? hh[2] : c[2];
        float a3 = (lq < 2) ? hh[3] : c[3];
        float a4 = (lq < 2) ? hh[4] : c[4];
        float v0 = (lq & 1) ? a3 : a0;
        float v1 = (lq & 1) ? a4 : a1;
        sb[0] = v0;
        sb[1] = v1;
        if (!(lq & 1)) sb[2] = a2;
        sb += NH;

        #pragma unroll
        for (int f = 0; f < NF; ++f) xv[f] = xn[f];
    }

    // ---- fc head (lane 0 of each 8-group has full h) ----
    if ((tid & 7) == 0) {
        float acc = fc_b[0];
        #pragma unroll
        for (int k = 0; k < NH; ++k) acc = fmaf(h[k], fc_w[k], acc);
        out[b] = acc;
    }
}

extern "C" void kernel_launch(void* const* d_in, const int* in_sizes, int n_in,
                              void* d_out, int out_size, void* d_ws, size_t ws_size,
                              hipStream_t stream) {
    const float* x    = (const float*)d_in[0];
    const float* wih  = (const float*)d_in[1];
    const float* whh  = (const float*)d_in[2];
    const float* bias = (const float*)d_in[3];
    const float* fcw  = (const float*)d_in[4];
    const float* fcb  = (const float*)d_in[5];
    float* out = (float*)d_out;

    const int threads = NB * 8;          // 8 lanes per batch element
    const int block = 256;
    lstm_fused8<<<threads / block, block, 0, stream>>>(x, wih, whh, bias, fcw, fcb, out);
}